// Round 5
// baseline (202.570 us; speedup 1.0000x reference)
//
#include <hip/hip_runtime.h>
#include <cstdint>
#include <cmath>

typedef unsigned short u16;
typedef short bf16x8 __attribute__((ext_vector_type(8)));
typedef float f32x4 __attribute__((ext_vector_type(4)));

#define T_DIM 2048
#define B_DIM 16
#define CIN 512
#define COUT 512
#define KIN 1536
#define NROWS (T_DIM * B_DIM)        /* 32768 */
#define UROWS ((T_DIM + 2) * B_DIM)  /* 32800 */

#define BM 256
#define BN 256
#define BK 64
#define NT (KIN / BK)                /* 24 K-tiles */

#define LOG2E 1.44269504088896f
#define LN2   0.69314718055995f

__device__ __forceinline__ float fast_exp2(float x) {
#if __has_builtin(__builtin_amdgcn_exp2f)
  return __builtin_amdgcn_exp2f(x);
#else
  return __builtin_exp2f(x);
#endif
}
__device__ __forceinline__ float fast_log2(float x) {
#if __has_builtin(__builtin_amdgcn_logf)
  return __builtin_amdgcn_logf(x);   // v_log_f32 = log2(x)
#else
  return __builtin_log2f(x);
#endif
}
__device__ __forceinline__ float fast_rcp(float x) {
  return __builtin_amdgcn_rcpf(x);
}

__device__ __forceinline__ u16 f2bf(float f) {
  unsigned u = __builtin_bit_cast(unsigned, f);
  u = (u + 0x7FFFu + ((u >> 16) & 1u)) >> 16;   // RNE
  return (u16)u;
}

typedef __attribute__((address_space(3))) unsigned int as3u32;
typedef __attribute__((address_space(1))) unsigned int as1u32;

// async global->LDS, 16B per lane; lds must be the wave-uniform base.
__device__ __forceinline__ void gload16(const u16* g, const u16* lds) {
#if __has_builtin(__builtin_amdgcn_global_load_lds)
  __builtin_amdgcn_global_load_lds((as1u32*)(uintptr_t)g,
                                   (as3u32*)(unsigned)(uintptr_t)lds, 16, 0, 0);
#else
  unsigned lane = __lane_id();
  ((uint4*)lds)[lane] = *(const uint4*)g;
#endif
}

// ---- K0: column inv-norms of weight_v [KIN, COUT], coalesced ----
__global__ __launch_bounds__(256) void k_colnorm(const float* __restrict__ wv,
                                                 float* __restrict__ invn) {
  __shared__ float part[4][64];
  int o0 = blockIdx.x * 64;
  int tx = threadIdx.x & 63, ty = threadIdx.x >> 6;
  float s = 0.f;
  for (int r = ty; r < KIN; r += 4) {
    float v = wv[(size_t)r * COUT + o0 + tx];
    s += v * v;
  }
  part[ty][tx] = s;
  __syncthreads();
  if (ty == 0) {
    float t = part[0][tx] + part[1][tx] + part[2][tx] + part[3][tx];
    invn[o0 + tx] = 1.f / fmaxf(sqrtf(t), 1e-15f);
  }
}

// ---- K0b: per-channel cosh/sinh of 2*bias ----
__global__ void k_chsh(const float* __restrict__ bias, float* __restrict__ ch,
                       float* __restrict__ sh) {
  int o = blockIdx.x * blockDim.x + threadIdx.x;
  if (o < COUT) {
    float d = 2.f * bias[o];
    float e = fast_exp2(d * LOG2E);
    float ie = fast_rcp(e);
    ch[o] = 0.5f * (e + ie);
    sh[o] = 0.5f * (e - ie);
  }
}

// ---- K1: W^T bf16: wt[o][i] = wv[i][o] * invn[o] ----
__global__ void k_wt(const float* __restrict__ wv, const float* __restrict__ invn,
                     u16* __restrict__ wt) {
  __shared__ float tile[64][65];
  int i0 = blockIdx.x * 64;
  int o0 = blockIdx.y * 64;
  int tx = threadIdx.x & 63, ty = threadIdx.x >> 6;  // 256 thr
  for (int r = ty; r < 64; r += 4)
    tile[r][tx] = wv[(size_t)(i0 + r) * COUT + o0 + tx];
  __syncthreads();
  for (int r = ty; r < 64; r += 4) {
    float inv = invn[o0 + r];
    wt[(size_t)(o0 + r) * KIN + i0 + tx] = f2bf(tile[tx][r] * inv);
  }
}

// ---- K2: u = logmap0(x)*BETA_RATIO -> bf16 [UROWS,512]; nsq fp32 per row ----
__global__ void k_logmap(const float* __restrict__ x, u16* __restrict__ U,
                         float* __restrict__ nsq, float beta_ratio) {
  int row = blockIdx.x;        // 0..32799 = t_pad*16 + b
  int t = row >> 4;
  int lane = threadIdx.x;      // 64
  uint4* urow = (uint4*)(U + (size_t)row * CIN);
  if (t == 0 || t == T_DIM + 1) {
    uint4 z; z.x = z.y = z.z = z.w = 0u;
    urow[lane] = z;
    if (lane == 0) nsq[row] = 0.f;
    return;
  }
  const float4* xr = (const float4*)(x + (size_t)(row - 16) * CIN);
  float4 a = xr[lane * 2];
  float4 b = xr[lane * 2 + 1];
  float s = a.x*a.x + a.y*a.y + a.z*a.z + a.w*a.w
          + b.x*b.x + b.y*b.y + b.z*b.z + b.w*b.w;
#pragma unroll
  for (int d = 1; d < 64; d <<= 1) s += __shfl_xor(s, d);
  float r = sqrtf(s);
  float yn = fmaxf(r, 1e-15f);
  float arg = fminf(yn, 1.0f - 1e-7f);
  // atanh(arg) = 0.5*ln((1+arg)/(1-arg)) via hw log2
  float at = 0.5f * LN2 * fast_log2((1.f + arg) * fast_rcp(1.f - arg));
  float f = at / yn * beta_ratio;
  union { u16 h[8]; uint4 v; } pk;
  pk.h[0] = f2bf(a.x * f); pk.h[1] = f2bf(a.y * f);
  pk.h[2] = f2bf(a.z * f); pk.h[3] = f2bf(a.w * f);
  pk.h[4] = f2bf(b.x * f); pk.h[5] = f2bf(b.y * f);
  pk.h[6] = f2bf(b.z * f); pk.h[7] = f2bf(b.w * f);
  urow[lane] = pk.v;
  if (lane == 0) nsq[row] = s * f * f;
}

// ---- K3: GEMM dot[m][o] = sum_k u_im2col[m][k] * wt[o][k] ----
// 256x256 tile, BK=64, 8 waves (2M x 4N, wave tile 128x64), LDS 128 KiB dbuf.
// Counted-vmcnt pipeline: STAGE(t+1) stays in flight across compute(t);
// raw s_barrier (no compiler vmcnt(0) drain). T2 both-sides chunk swizzle
// (phys chunk = c ^ (row&7)): pre-swizzled global src, swizzled frag reads.
__global__ __launch_bounds__(512, 2) void k_gemm(const u16* __restrict__ U,
                                                 const u16* __restrict__ WT,
                                                 float* __restrict__ out) {
  __shared__ u16 lA[2][BM * BK];   // 2 x 32 KiB
  __shared__ u16 lB[2][BN * BK];   // 2 x 32 KiB
  int bid = blockIdx.x;
  // XCD-contiguous: 32 consecutive wgids per XCD; bn-pairs adjacent.
  int wgid = (bid & 7) * 32 + (bid >> 3);
  int bm = wgid >> 1, bn = wgid & 1;
  int tid = threadIdx.x;
  int lane = tid & 63;
  int wid = tid >> 6;
  int wr = wid >> 2, wc = wid & 3;      // wave tile: 128 rows x 64 cols
  int lr = lane & 15;
  int chSw = (tid & 7) ^ ((tid >> 3) & 7);   // staging: pre-swizzled src chunk
  int srow = tid >> 3;                        // staging row within round
  // frag read phys chunk offsets (u16 units)
  int pc0 = (((lane >> 4)) ^ (lr & 7)) << 3;
  int pc1 = (((lane >> 4) | 4) ^ (lr & 7)) << 3;

  f32x4 acc[8][4] = {};
  const u16* gB0 = WT + (size_t)(bn * 256) * KIN;

  auto STAGE = [&](int t, int p) {
    int seg = t >> 3;                   // conv tap 0..2
    int c0 = (t & 7) << 6;              // col offset within tap
    const u16* gA = U + (size_t)(bm * 256 + seg * 16) * 512 + c0 + chSw * 8;
    const u16* gB = gB0 + t * 64 + chSw * 8;
#pragma unroll
    for (int r = 0; r < 4; ++r) {
      int row = r * 64 + srow;
      gload16(gA + (size_t)row * 512, &lA[p][(r * 64 + wid * 8) * BK]);
      gload16(gB + (size_t)row * KIN, &lB[p][(r * 64 + wid * 8) * BK]);
    }
  };

  STAGE(0, 0);
  for (int t = 0; t < NT; ++t) {
    int p = t & 1;
    if (t < NT - 1) {
      STAGE(t + 1, p ^ 1);
      asm volatile("s_waitcnt vmcnt(8)" ::: "memory");  // tile t landed; t+1 in flight
    } else {
      asm volatile("s_waitcnt vmcnt(0)" ::: "memory");
    }
    asm volatile("s_barrier" ::: "memory");
    const u16* pA = &lA[p][(wr * 128 + lr) * BK];
    const u16* pB = &lB[p][(wc * 64 + lr) * BK];
#pragma unroll
    for (int kk = 0; kk < 2; ++kk) {
      int pc = kk ? pc1 : pc0;
      bf16x8 af[8], bf[4];
#pragma unroll
      for (int i = 0; i < 8; ++i) af[i] = *(const bf16x8*)(pA + i * 16 * BK + pc);
#pragma unroll
      for (int i = 0; i < 4; ++i) bf[i] = *(const bf16x8*)(pB + i * 16 * BK + pc);
      __builtin_amdgcn_s_setprio(1);
#pragma unroll
      for (int mi = 0; mi < 8; ++mi)
#pragma unroll
        for (int ni = 0; ni < 4; ++ni)
          acc[mi][ni] = __builtin_amdgcn_mfma_f32_16x16x32_bf16(
              af[mi], bf[ni], acc[mi][ni], 0, 0, 0);
      __builtin_amdgcn_s_setprio(0);
    }
    asm volatile("s_waitcnt lgkmcnt(0)" ::: "memory");  // reads done before reuse
    asm volatile("s_barrier" ::: "memory");
  }

  int orow = bm * 256 + wr * 128 + ((lane >> 4) << 2);
  int ocol = bn * 256 + wc * 64 + lr;
#pragma unroll
  for (int mi = 0; mi < 8; ++mi)
#pragma unroll
    for (int ni = 0; ni < 4; ++ni)
#pragma unroll
      for (int j = 0; j < 4; ++j)
        out[(size_t)(orow + mi * 16 + j) * COUT + (ocol + ni * 16)] = acc[mi][ni][j];
}

// ---- K4: in-place epilogue on dot rows: poincare_linear tail + project ----
// All transcendentals via hw v_log_f32/v_exp_f32/v_rcp_f32:
//   sinh(2g*asinh(z)) = 0.5*(E - 1/E),  E = w^(2g),  w = z + sqrt(z^2+1)
__global__ __launch_bounds__(128) void k_epi(float* __restrict__ out,
                                             const float* __restrict__ nsq,
                                             const float* __restrict__ wg,
                                             const float* __restrict__ chv,
                                             const float* __restrict__ shv) {
  int m = blockIdx.x;
  int tid = threadIdx.x;                 // 128
  int lane = tid & 63, wv_ = tid >> 6;
  float un2 = nsq[m] + nsq[m + 16] + nsq[m + 32];
  float un = sqrtf(un2);
  float unc = fmaxf(un, 1e-15f);
  // tanh(unc) = (e2-1)/(e2+1), e2 = exp(2*unc)
  float e2 = fast_exp2(unc * (2.f * LOG2E));
  float th = (e2 - 1.f) * fast_rcp(e2 + 1.f);
  float sxp = th * fast_rcp(unc);        // expmap0 scale (RC=1)
  float cx2 = sxp * sxp * un2;           // ||rcx||^2
  float iden = fast_rcp(fmaxf(1.f - cx2, 1e-15f));

  float4 dv = ((const float4*)(out + (size_t)m * COUT))[tid];
  float4 gv = ((const float4*)wg)[tid];
  float4 cv = ((const float4*)chv)[tid];
  float4 sv = ((const float4*)shv)[tid];
  float dot[4] = {dv.x, dv.y, dv.z, dv.w};
  float gvr[4] = {gv.x, gv.y, gv.z, gv.w};
  float chr[4] = {cv.x, cv.y, cv.z, cv.w};
  float shr[4] = {sv.x, sv.y, sv.z, sv.w};
  float y[4];
  float opc = 1.f + cx2;
#pragma unroll
  for (int e = 0; e < 4; ++e) {
    float num = 2.f * (sxp * dot[e]) * chr[e] - opc * shr[e];
    float z = num * iden;
    // y = sinh(2g * asinh(z))
    float w = z + sqrtf(fmaf(z, z, 1.f));
    float l = fast_log2(w);
    float E = fast_exp2((2.f * gvr[e]) * l);
    y[e] = 0.5f * (E - fast_rcp(E));
  }
  float ssl = y[0]*y[0] + y[1]*y[1] + y[2]*y[2] + y[3]*y[3];
#pragma unroll
  for (int d = 1; d < 64; d <<= 1) ssl += __shfl_xor(ssl, d);
  __shared__ float red[2];
  if (lane == 0) red[wv_] = ssl;
  __syncthreads();
  float ss = red[0] + red[1];
  float denom = 1.f + sqrtf(1.f + ss);
  float idn = 1.f / denom;
  float nrm = fmaxf(sqrtf(ss) * idn, 1e-15f);
  float maxn = 1.0f - 4e-3f;
  float scale = (nrm > maxn) ? (maxn / nrm) : 1.f;
  scale *= idn;
  float4 ov;
  ov.x = y[0] * scale;
  ov.y = y[1] * scale;
  ov.z = y[2] * scale;
  ov.w = y[3] * scale;
  ((float4*)(out + (size_t)m * COUT))[tid] = ov;
}

extern "C" void kernel_launch(void* const* d_in, const int* in_sizes, int n_in,
                              void* d_out, int out_size, void* d_ws, size_t ws_size,
                              hipStream_t stream) {
  const float* x    = (const float*)d_in[0];
  const float* wg   = (const float*)d_in[1];
  const float* wv   = (const float*)d_in[2];
  const float* bias = (const float*)d_in[3];
  float* out = (float*)d_out;

  char* ws = (char*)d_ws;
  u16*   U    = (u16*)(ws);                    // 2050*16*512 bf16 = 33,587,200 B
  float* NSQ  = (float*)(ws + 33587200);       // 32800 f32      =    131,200 B
  u16*   WT   = (u16*)(ws + 33718400);         // 512*1536 bf16  =  1,572,864 B
  float* INVN = (float*)(ws + 35291264);       // 512 f32
  float* CH   = (float*)(ws + 35293312);       // 512 f32
  float* SH   = (float*)(ws + 35295360);       // 512 f32

  double lb = (lgamma(768.0) + lgamma(0.5) - lgamma(768.5))
            - (lgamma(256.0) + lgamma(0.5) - lgamma(256.5));
  float beta_ratio = (float)exp(lb);           // beta(768,.5)/beta(256,.5)

  k_colnorm<<<COUT / 64, 256, 0, stream>>>(wv, INVN);
  k_chsh<<<COUT / 128, 128, 0, stream>>>(bias, CH, SH);
  k_wt<<<dim3(KIN / 64, COUT / 64), 256, 0, stream>>>(wv, INVN, WT);
  k_logmap<<<UROWS, 64, 0, stream>>>(x, U, NSQ, beta_ratio);
  k_gemm<<<(NROWS / BM) * (COUT / BN), 512, 0, stream>>>(U, WT, out);
  k_epi<<<NROWS, 128, 0, stream>>>(out, NSQ, wg, CH, SH);
}

// Round 6
// 117.470 us; speedup vs baseline: 1.7244x; 1.7244x over previous
//
#include <hip/hip_runtime.h>
#include <cstdint>
#include <cmath>

typedef unsigned short u16;
typedef short bf16x8 __attribute__((ext_vector_type(8)));
typedef float f32x4 __attribute__((ext_vector_type(4)));

#define T_DIM 2048
#define B_DIM 16
#define CIN 512
#define COUT 512
#define KIN 1536
#define NROWS (T_DIM * B_DIM)        /* 32768 */
#define UROWS ((T_DIM + 2) * B_DIM)  /* 32800 */

#define BM 256
#define BN 256
#define BK 64
#define NT (KIN / BK)                /* 24 K-tiles */

#define LOG2E 1.44269504088896f
#define LN2   0.69314718055995f

__device__ __forceinline__ float fast_exp2(float x) {
#if __has_builtin(__builtin_amdgcn_exp2f)
  return __builtin_amdgcn_exp2f(x);
#else
  return __builtin_exp2f(x);
#endif
}
__device__ __forceinline__ float fast_log2(float x) {
#if __has_builtin(__builtin_amdgcn_logf)
  return __builtin_amdgcn_logf(x);   // v_log_f32 = log2(x)
#else
  return __builtin_log2f(x);
#endif
}
__device__ __forceinline__ float fast_rcp(float x) {
  return __builtin_amdgcn_rcpf(x);
}

__device__ __forceinline__ u16 f2bf(float f) {
  unsigned u = __builtin_bit_cast(unsigned, f);
  u = (u + 0x7FFFu + ((u >> 16) & 1u)) >> 16;   // RNE
  return (u16)u;
}

typedef __attribute__((address_space(3))) unsigned int as3u32;
typedef __attribute__((address_space(1))) unsigned int as1u32;

// async global->LDS, 16B per lane; lds must be the wave-uniform base.
__device__ __forceinline__ void gload16(const u16* g, const u16* lds) {
#if __has_builtin(__builtin_amdgcn_global_load_lds)
  __builtin_amdgcn_global_load_lds((as1u32*)(uintptr_t)g,
                                   (as3u32*)(unsigned)(uintptr_t)lds, 16, 0, 0);
#else
  unsigned lane = __lane_id();
  ((uint4*)lds)[lane] = *(const uint4*)g;
#endif
}

// ---- K0a: partial column sumsq of weight_v [KIN, COUT], coalesced ----
// grid (COUT/256, KIN/64), block 256: partial[by][o] = sum over 64 K-rows.
__global__ __launch_bounds__(256) void k_colnorm(const float* __restrict__ wv,
                                                 float* __restrict__ partial) {
  int o = blockIdx.x * 256 + threadIdx.x;
  int r0 = blockIdx.y * 64;
  float s = 0.f;
#pragma unroll 8
  for (int r = 0; r < 64; ++r) {
    float v = wv[(size_t)(r0 + r) * COUT + o];
    s += v * v;
  }
  partial[(size_t)blockIdx.y * COUT + o] = s;
}

// ---- K0c: finalize invn[o] = 1/max(sqrt(sum partial),eps), deterministic ----
__global__ __launch_bounds__(256) void k_fin(const float* __restrict__ partial,
                                             float* __restrict__ invn) {
  int o = blockIdx.x * 256 + threadIdx.x;
  float s = 0.f;
#pragma unroll
  for (int j = 0; j < KIN / 64; ++j) s += partial[(size_t)j * COUT + o];
  invn[o] = 1.f / fmaxf(sqrtf(s), 1e-15f);
}

// ---- K0b: per-channel cosh/sinh of 2*bias ----
__global__ void k_chsh(const float* __restrict__ bias, float* __restrict__ ch,
                       float* __restrict__ sh) {
  int o = blockIdx.x * blockDim.x + threadIdx.x;
  if (o < COUT) {
    float d = 2.f * bias[o];
    float e = fast_exp2(d * LOG2E);
    float ie = fast_rcp(e);
    ch[o] = 0.5f * (e + ie);
    sh[o] = 0.5f * (e - ie);
  }
}

// ---- K1: W^T bf16: wt[o][i] = wv[i][o] * invn[o] ----
__global__ void k_wt(const float* __restrict__ wv, const float* __restrict__ invn,
                     u16* __restrict__ wt) {
  __shared__ float tile[64][65];
  int i0 = blockIdx.x * 64;
  int o0 = blockIdx.y * 64;
  int tx = threadIdx.x & 63, ty = threadIdx.x >> 6;  // 256 thr
  for (int r = ty; r < 64; r += 4)
    tile[r][tx] = wv[(size_t)(i0 + r) * COUT + o0 + tx];
  __syncthreads();
  for (int r = ty; r < 64; r += 4) {
    float inv = invn[o0 + r];
    wt[(size_t)(o0 + r) * KIN + i0 + tx] = f2bf(tile[tx][r] * inv);
  }
}

// ---- K2: u = logmap0(x)*BETA_RATIO -> bf16 [UROWS,512]; nsq fp32 per row ----
__global__ void k_logmap(const float* __restrict__ x, u16* __restrict__ U,
                         float* __restrict__ nsq, float beta_ratio) {
  int row = blockIdx.x;        // 0..32799 = t_pad*16 + b
  int t = row >> 4;
  int lane = threadIdx.x;      // 64
  uint4* urow = (uint4*)(U + (size_t)row * CIN);
  if (t == 0 || t == T_DIM + 1) {
    uint4 z; z.x = z.y = z.z = z.w = 0u;
    urow[lane] = z;
    if (lane == 0) nsq[row] = 0.f;
    return;
  }
  const float4* xr = (const float4*)(x + (size_t)(row - 16) * CIN);
  float4 a = xr[lane * 2];
  float4 b = xr[lane * 2 + 1];
  float s = a.x*a.x + a.y*a.y + a.z*a.z + a.w*a.w
          + b.x*b.x + b.y*b.y + b.z*b.z + b.w*b.w;
#pragma unroll
  for (int d = 1; d < 64; d <<= 1) s += __shfl_xor(s, d);
  float r = sqrtf(s);
  float yn = fmaxf(r, 1e-15f);
  float arg = fminf(yn, 1.0f - 1e-7f);
  // atanh(arg) = 0.5*ln((1+arg)/(1-arg)) via hw log2
  float at = 0.5f * LN2 * fast_log2((1.f + arg) * fast_rcp(1.f - arg));
  float f = at / yn * beta_ratio;
  union { u16 h[8]; uint4 v; } pk;
  pk.h[0] = f2bf(a.x * f); pk.h[1] = f2bf(a.y * f);
  pk.h[2] = f2bf(a.z * f); pk.h[3] = f2bf(a.w * f);
  pk.h[4] = f2bf(b.x * f); pk.h[5] = f2bf(b.y * f);
  pk.h[6] = f2bf(b.z * f); pk.h[7] = f2bf(b.w * f);
  urow[lane] = pk.v;
  if (lane == 0) nsq[row] = s * f * f;
}

// ---- K3: GEMM dot[m][o] = sum_k u_im2col[m][k] * wt[o][k] ----
// 256x256 tile, BK=64, 8 waves (2M x 4N, wave tile 128x64), LDS 128 KiB dbuf.
// Counted-vmcnt pipeline: STAGE(t+1) stays in flight across compute(t);
// raw s_barrier (no compiler vmcnt(0) drain). T2 both-sides chunk swizzle
// (phys chunk = c ^ (row&7)): pre-swizzled global src, swizzled frag reads.
__global__ __launch_bounds__(512, 2) void k_gemm(const u16* __restrict__ U,
                                                 const u16* __restrict__ WT,
                                                 float* __restrict__ out) {
  __shared__ u16 lA[2][BM * BK];   // 2 x 32 KiB
  __shared__ u16 lB[2][BN * BK];   // 2 x 32 KiB
  int bid = blockIdx.x;
  // XCD-contiguous: 32 consecutive wgids per XCD; bn-pairs adjacent.
  int wgid = (bid & 7) * 32 + (bid >> 3);
  int bm = wgid >> 1, bn = wgid & 1;
  int tid = threadIdx.x;
  int lane = tid & 63;
  int wid = tid >> 6;
  int wr = wid >> 2, wc = wid & 3;      // wave tile: 128 rows x 64 cols
  int lr = lane & 15;
  int chSw = (tid & 7) ^ ((tid >> 3) & 7);   // staging: pre-swizzled src chunk
  int srow = tid >> 3;                        // staging row within round
  // frag read phys chunk offsets (u16 units)
  int pc0 = (((lane >> 4)) ^ (lr & 7)) << 3;
  int pc1 = (((lane >> 4) | 4) ^ (lr & 7)) << 3;

  f32x4 acc[8][4] = {};
  const u16* gB0 = WT + (size_t)(bn * 256) * KIN;

  auto STAGE = [&](int t, int p) {
    int seg = t >> 3;                   // conv tap 0..2
    int c0 = (t & 7) << 6;              // col offset within tap
    const u16* gA = U + (size_t)(bm * 256 + seg * 16) * 512 + c0 + chSw * 8;
    const u16* gB = gB0 + t * 64 + chSw * 8;
#pragma unroll
    for (int r = 0; r < 4; ++r) {
      int row = r * 64 + srow;
      gload16(gA + (size_t)row * 512, &lA[p][(r * 64 + wid * 8) * BK]);
      gload16(gB + (size_t)row * KIN, &lB[p][(r * 64 + wid * 8) * BK]);
    }
  };

  STAGE(0, 0);
  for (int t = 0; t < NT; ++t) {
    int p = t & 1;
    if (t < NT - 1) {
      STAGE(t + 1, p ^ 1);
      asm volatile("s_waitcnt vmcnt(8)" ::: "memory");  // tile t landed; t+1 in flight
    } else {
      asm volatile("s_waitcnt vmcnt(0)" ::: "memory");
    }
    asm volatile("s_barrier" ::: "memory");
    const u16* pA = &lA[p][(wr * 128 + lr) * BK];
    const u16* pB = &lB[p][(wc * 64 + lr) * BK];
#pragma unroll
    for (int kk = 0; kk < 2; ++kk) {
      int pc = kk ? pc1 : pc0;
      bf16x8 af[8], bf[4];
#pragma unroll
      for (int i = 0; i < 8; ++i) af[i] = *(const bf16x8*)(pA + i * 16 * BK + pc);
#pragma unroll
      for (int i = 0; i < 4; ++i) bf[i] = *(const bf16x8*)(pB + i * 16 * BK + pc);
      __builtin_amdgcn_s_setprio(1);
#pragma unroll
      for (int mi = 0; mi < 8; ++mi)
#pragma unroll
        for (int ni = 0; ni < 4; ++ni)
          acc[mi][ni] = __builtin_amdgcn_mfma_f32_16x16x32_bf16(
              af[mi], bf[ni], acc[mi][ni], 0, 0, 0);
      __builtin_amdgcn_s_setprio(0);
    }
    asm volatile("s_waitcnt lgkmcnt(0)" ::: "memory");  // reads done before reuse
    asm volatile("s_barrier" ::: "memory");
  }

  int orow = bm * 256 + wr * 128 + ((lane >> 4) << 2);
  int ocol = bn * 256 + wc * 64 + lr;
#pragma unroll
  for (int mi = 0; mi < 8; ++mi)
#pragma unroll
    for (int ni = 0; ni < 4; ++ni)
#pragma unroll
      for (int j = 0; j < 4; ++j)
        out[(size_t)(orow + mi * 16 + j) * COUT + (ocol + ni * 16)] = acc[mi][ni][j];
}

// ---- K4: in-place epilogue on dot rows: poincare_linear tail + project ----
// All transcendentals via hw v_log_f32/v_exp_f32/v_rcp_f32:
//   sinh(2g*asinh(z)) = 0.5*(E - 1/E),  E = w^(2g),  w = z + sqrt(z^2+1)
__global__ __launch_bounds__(128) void k_epi(float* __restrict__ out,
                                             const float* __restrict__ nsq,
                                             const float* __restrict__ wg,
                                             const float* __restrict__ chv,
                                             const float* __restrict__ shv) {
  int m = blockIdx.x;
  int tid = threadIdx.x;                 // 128
  int lane = tid & 63, wv_ = tid >> 6;
  float un2 = nsq[m] + nsq[m + 16] + nsq[m + 32];
  float un = sqrtf(un2);
  float unc = fmaxf(un, 1e-15f);
  // tanh(unc) = (e2-1)/(e2+1), e2 = exp(2*unc)
  float e2 = fast_exp2(unc * (2.f * LOG2E));
  float th = (e2 - 1.f) * fast_rcp(e2 + 1.f);
  float sxp = th * fast_rcp(unc);        // expmap0 scale (RC=1)
  float cx2 = sxp * sxp * un2;           // ||rcx||^2
  float iden = fast_rcp(fmaxf(1.f - cx2, 1e-15f));

  float4 dv = ((const float4*)(out + (size_t)m * COUT))[tid];
  float4 gv = ((const float4*)wg)[tid];
  float4 cv = ((const float4*)chv)[tid];
  float4 sv = ((const float4*)shv)[tid];
  float dot[4] = {dv.x, dv.y, dv.z, dv.w};
  float gvr[4] = {gv.x, gv.y, gv.z, gv.w};
  float chr[4] = {cv.x, cv.y, cv.z, cv.w};
  float shr[4] = {sv.x, sv.y, sv.z, sv.w};
  float y[4];
  float opc = 1.f + cx2;
#pragma unroll
  for (int e = 0; e < 4; ++e) {
    float num = 2.f * (sxp * dot[e]) * chr[e] - opc * shr[e];
    float z = num * iden;
    // y = sinh(2g * asinh(z))
    float w = z + sqrtf(fmaf(z, z, 1.f));
    float l = fast_log2(w);
    float E = fast_exp2((2.f * gvr[e]) * l);
    y[e] = 0.5f * (E - fast_rcp(E));
  }
  float ssl = y[0]*y[0] + y[1]*y[1] + y[2]*y[2] + y[3]*y[3];
#pragma unroll
  for (int d = 1; d < 64; d <<= 1) ssl += __shfl_xor(ssl, d);
  __shared__ float red[2];
  if (lane == 0) red[wv_] = ssl;
  __syncthreads();
  float ss = red[0] + red[1];
  float denom = 1.f + sqrtf(1.f + ss);
  float idn = 1.f / denom;
  float nrm = fmaxf(sqrtf(ss) * idn, 1e-15f);
  float maxn = 1.0f - 4e-3f;
  float scale = (nrm > maxn) ? (maxn / nrm) : 1.f;
  scale *= idn;
  float4 ov;
  ov.x = y[0] * scale;
  ov.y = y[1] * scale;
  ov.z = y[2] * scale;
  ov.w = y[3] * scale;
  ((float4*)(out + (size_t)m * COUT))[tid] = ov;
}

extern "C" void kernel_launch(void* const* d_in, const int* in_sizes, int n_in,
                              void* d_out, int out_size, void* d_ws, size_t ws_size,
                              hipStream_t stream) {
  const float* x    = (const float*)d_in[0];
  const float* wg   = (const float*)d_in[1];
  const float* wv   = (const float*)d_in[2];
  const float* bias = (const float*)d_in[3];
  float* out = (float*)d_out;

  char* ws = (char*)d_ws;
  u16*   U    = (u16*)(ws);                    // 2050*16*512 bf16 = 33,587,200 B
  float* NSQ  = (float*)(ws + 33587200);       // 32800 f32      =    131,200 B
  u16*   WT   = (u16*)(ws + 33718400);         // 512*1536 bf16  =  1,572,864 B
  float* INVN = (float*)(ws + 35291264);       // 512 f32
  float* CH   = (float*)(ws + 35293312);       // 512 f32
  float* SH   = (float*)(ws + 35295360);       // 512 f32
  float* PART = (float*)(ws + 35297408);       // 24*512 f32 = 49,152 B

  double lb = (lgamma(768.0) + lgamma(0.5) - lgamma(768.5))
            - (lgamma(256.0) + lgamma(0.5) - lgamma(256.5));
  float beta_ratio = (float)exp(lb);           // beta(768,.5)/beta(256,.5)

  k_colnorm<<<dim3(COUT / 256, KIN / 64), 256, 0, stream>>>(wv, PART);
  k_fin<<<COUT / 256, 256, 0, stream>>>(PART, INVN);
  k_chsh<<<COUT / 128, 128, 0, stream>>>(bias, CH, SH);
  k_wt<<<dim3(KIN / 64, COUT / 64), 256, 0, stream>>>(wv, INVN, WT);
  k_logmap<<<UROWS, 64, 0, stream>>>(x, U, NSQ, beta_ratio);
  k_gemm<<<(NROWS / BM) * (COUT / BN), 512, 0, stream>>>(U, WT, out);
  k_epi<<<NROWS, 128, 0, stream>>>(out, NSQ, wg, CH, SH);
}

// Round 7
// 116.735 us; speedup vs baseline: 1.7353x; 1.0063x over previous
//
#include <hip/hip_runtime.h>
#include <cstdint>
#include <cmath>

typedef unsigned short u16;
typedef short bf16x8 __attribute__((ext_vector_type(8)));
typedef float f32x4 __attribute__((ext_vector_type(4)));

#define T_DIM 2048
#define B_DIM 16
#define CIN 512
#define COUT 512
#define KIN 1536
#define NROWS (T_DIM * B_DIM)        /* 32768 */
#define UROWS ((T_DIM + 2) * B_DIM)  /* 32800 */

#define BM 128
#define BK 64
#define NT (KIN / BK)                /* 24 K-tiles */

#define LOG2E 1.44269504088896f
#define LN2   0.69314718055995f

__device__ __forceinline__ float fast_exp2(float x) {
#if __has_builtin(__builtin_amdgcn_exp2f)
  return __builtin_amdgcn_exp2f(x);
#else
  return __builtin_exp2f(x);
#endif
}
__device__ __forceinline__ float fast_log2(float x) {
#if __has_builtin(__builtin_amdgcn_logf)
  return __builtin_amdgcn_logf(x);   // v_log_f32 = log2(x)
#else
  return __builtin_log2f(x);
#endif
}
__device__ __forceinline__ float fast_rcp(float x) {
  return __builtin_amdgcn_rcpf(x);
}

__device__ __forceinline__ u16 f2bf(float f) {
  unsigned u = __builtin_bit_cast(unsigned, f);
  u = (u + 0x7FFFu + ((u >> 16) & 1u)) >> 16;   // RNE
  return (u16)u;
}

typedef __attribute__((address_space(3))) unsigned int as3u32;
typedef __attribute__((address_space(1))) unsigned int as1u32;

// async global->LDS, 16B per lane; lds must be the wave-uniform base.
__device__ __forceinline__ void gload16(const u16* g, const u16* lds) {
#if __has_builtin(__builtin_amdgcn_global_load_lds)
  __builtin_amdgcn_global_load_lds((as1u32*)(uintptr_t)g,
                                   (as3u32*)(unsigned)(uintptr_t)lds, 16, 0, 0);
#else
  unsigned lane = __lane_id();
  ((uint4*)lds)[lane] = *(const uint4*)g;
#endif
}

// ---- K0a: partial column sumsq of weight_v [KIN, COUT], coalesced ----
__global__ __launch_bounds__(256) void k_colnorm(const float* __restrict__ wv,
                                                 float* __restrict__ partial) {
  int o = blockIdx.x * 256 + threadIdx.x;
  int r0 = blockIdx.y * 64;
  float s = 0.f;
#pragma unroll 8
  for (int r = 0; r < 64; ++r) {
    float v = wv[(size_t)(r0 + r) * COUT + o];
    s += v * v;
  }
  partial[(size_t)blockIdx.y * COUT + o] = s;
}

// ---- K0c: finalize invn ----
__global__ __launch_bounds__(256) void k_fin(const float* __restrict__ partial,
                                             float* __restrict__ invn) {
  int o = blockIdx.x * 256 + threadIdx.x;
  float s = 0.f;
#pragma unroll
  for (int j = 0; j < KIN / 64; ++j) s += partial[(size_t)j * COUT + o];
  invn[o] = 1.f / fmaxf(sqrtf(s), 1e-15f);
}

// ---- K0b: per-channel cosh/sinh of 2*bias ----
__global__ void k_chsh(const float* __restrict__ bias, float* __restrict__ ch,
                       float* __restrict__ sh) {
  int o = blockIdx.x * blockDim.x + threadIdx.x;
  if (o < COUT) {
    float d = 2.f * bias[o];
    float e = fast_exp2(d * LOG2E);
    float ie = fast_rcp(e);
    ch[o] = 0.5f * (e + ie);
    sh[o] = 0.5f * (e - ie);
  }
}

// ---- K1: W^T bf16: wt[o][i] = wv[i][o] * invn[o] ----
__global__ void k_wt(const float* __restrict__ wv, const float* __restrict__ invn,
                     u16* __restrict__ wt) {
  __shared__ float tile[64][65];
  int i0 = blockIdx.x * 64;
  int o0 = blockIdx.y * 64;
  int tx = threadIdx.x & 63, ty = threadIdx.x >> 6;  // 256 thr
  for (int r = ty; r < 64; r += 4)
    tile[r][tx] = wv[(size_t)(i0 + r) * COUT + o0 + tx];
  __syncthreads();
  for (int r = ty; r < 64; r += 4) {
    float inv = invn[o0 + r];
    wt[(size_t)(o0 + r) * KIN + i0 + tx] = f2bf(tile[tx][r] * inv);
  }
}

// ---- K2: u = logmap0(x)*BETA_RATIO -> bf16 [UROWS,512]; nsq fp32 per row ----
__global__ void k_logmap(const float* __restrict__ x, u16* __restrict__ U,
                         float* __restrict__ nsq, float beta_ratio) {
  int row = blockIdx.x;        // 0..32799 = t_pad*16 + b
  int t = row >> 4;
  int lane = threadIdx.x;      // 64
  uint4* urow = (uint4*)(U + (size_t)row * CIN);
  if (t == 0 || t == T_DIM + 1) {
    uint4 z; z.x = z.y = z.z = z.w = 0u;
    urow[lane] = z;
    if (lane == 0) nsq[row] = 0.f;
    return;
  }
  const float4* xr = (const float4*)(x + (size_t)(row - 16) * CIN);
  float4 a = xr[lane * 2];
  float4 b = xr[lane * 2 + 1];
  float s = a.x*a.x + a.y*a.y + a.z*a.z + a.w*a.w
          + b.x*b.x + b.y*b.y + b.z*b.z + b.w*b.w;
#pragma unroll
  for (int d = 1; d < 64; d <<= 1) s += __shfl_xor(s, d);
  float r = sqrtf(s);
  float yn = fmaxf(r, 1e-15f);
  float arg = fminf(yn, 1.0f - 1e-7f);
  float at = 0.5f * LN2 * fast_log2((1.f + arg) * fast_rcp(1.f - arg));
  float f = at / yn * beta_ratio;
  union { u16 h[8]; uint4 v; } pk;
  pk.h[0] = f2bf(a.x * f); pk.h[1] = f2bf(a.y * f);
  pk.h[2] = f2bf(a.z * f); pk.h[3] = f2bf(a.w * f);
  pk.h[4] = f2bf(b.x * f); pk.h[5] = f2bf(b.y * f);
  pk.h[6] = f2bf(b.z * f); pk.h[7] = f2bf(b.w * f);
  urow[lane] = pk.v;
  if (lane == 0) nsq[row] = s * f * f;
}

// ---- K2b: per-output-row constants R1 = 2*sxp*iden, R2 = (1+cx2)*iden ----
__global__ __launch_bounds__(256) void k_rows(const float* __restrict__ nsq,
                                              float* __restrict__ R1,
                                              float* __restrict__ R2) {
  int m = blockIdx.x * 256 + threadIdx.x;
  float un2 = nsq[m] + nsq[m + 16] + nsq[m + 32];
  float un = sqrtf(un2);
  float unc = fmaxf(un, 1e-15f);
  float e2 = fast_exp2(unc * (2.f * LOG2E));
  float th = (e2 - 1.f) * fast_rcp(e2 + 1.f);
  float sxp = th * fast_rcp(unc);        // expmap0 scale (RC=1)
  float cx2 = sxp * sxp * un2;           // ||rcx||^2
  float iden = fast_rcp(fmaxf(1.f - cx2, 1e-15f));
  R1[m] = 2.f * sxp * iden;
  R2[m] = (1.f + cx2) * iden;
}

// ---- K3: fused GEMM + poincare epilogue ----
// Block = 128 rows x 512 cols (full output rows). 8 waves (2M x 4N),
// wave tile 64x128, acc[4][8]. A double-buffered (counted vmcnt), B
// single-buffered (L2-hot, restaged per K-tile after compute barrier).
// T2 both-sides chunk swizzle (phys chunk = c ^ (row&7)). After the K-loop:
// y = sinh(2g*asinh(z)) per element via hw log2/exp2, per-row sum(y^2) via
// shfl_xor(16-lane) + LDS scratch, then project and store final out.
__global__ __launch_bounds__(512, 2) void k_gemm(const u16* __restrict__ U,
                                                 const u16* __restrict__ WT,
                                                 const float* __restrict__ R1,
                                                 const float* __restrict__ R2,
                                                 const float* __restrict__ wg,
                                                 const float* __restrict__ chv,
                                                 const float* __restrict__ shv,
                                                 float* __restrict__ out) {
  __shared__ u16 lA[2][BM * BK];   // 2 x 16 KiB
  __shared__ u16 lB[COUT * BK];    // 64 KiB, single buffer
  int bm = blockIdx.x;             // 256 blocks, 128 rows each
  int tid = threadIdx.x;
  int lane = tid & 63;
  int wid = tid >> 6;
  int wr = wid >> 2, wc = wid & 3;      // wave tile: 64 rows x 128 cols
  int lr = lane & 15;
  int srow = tid >> 3;                  // staging row within round (0..63)
  int chSw = (tid & 7) ^ (srow & 7);    // pre-swizzled global src chunk
  // frag read phys chunk offsets (u16 units): p = (c | kk*4) ^ (lr&7)
  int pc0 = (((lane >> 4)) ^ (lr & 7)) << 3;
  int pc1 = (((lane >> 4) | 4) ^ (lr & 7)) << 3;

  f32x4 acc[4][8] = {};

  auto STAGE_A = [&](int t, int p) {
    int seg = t >> 3;                   // conv tap 0..2
    int c0 = (t & 7) << 6;              // col offset within tap
    const u16* gA = U + (size_t)(bm * BM + seg * 16) * 512 + c0 + chSw * 8;
#pragma unroll
    for (int r = 0; r < 2; ++r) {
      int row = r * 64 + srow;
      gload16(gA + (size_t)row * 512, &lA[p][(r * 64 + wid * 8) * BK]);
    }
  };
  auto STAGE_B = [&](int t) {
    const u16* gB = WT + (size_t)t * 64 + chSw * 8;
#pragma unroll
    for (int r = 0; r < 8; ++r) {
      int row = r * 64 + srow;
      gload16(gB + (size_t)row * KIN, &lB[(r * 64 + wid * 8) * BK]);
    }
  };

  STAGE_A(0, 0);
  STAGE_B(0);
  asm volatile("s_waitcnt vmcnt(0)" ::: "memory");
  asm volatile("s_barrier" ::: "memory");

  for (int t = 0; t < NT; ++t) {
    int p = t & 1;
    if (t < NT - 1) STAGE_A(t + 1, p ^ 1);   // 2 loads stay in flight
    const u16* pA = &lA[p][(wr * 64 + lr) * BK];
    const u16* pB = &lB[(wc * 128 + lr) * BK];
#pragma unroll
    for (int kk = 0; kk < 2; ++kk) {
      int pc = kk ? pc1 : pc0;
      bf16x8 af[4], bf[8];
#pragma unroll
      for (int i = 0; i < 4; ++i) af[i] = *(const bf16x8*)(pA + i * 16 * BK + pc);
#pragma unroll
      for (int i = 0; i < 8; ++i) bf[i] = *(const bf16x8*)(pB + i * 16 * BK + pc);
      __builtin_amdgcn_s_setprio(1);
#pragma unroll
      for (int mi = 0; mi < 4; ++mi)
#pragma unroll
        for (int ni = 0; ni < 8; ++ni)
          acc[mi][ni] = __builtin_amdgcn_mfma_f32_16x16x32_bf16(
              af[mi], bf[ni], acc[mi][ni], 0, 0, 0);
      __builtin_amdgcn_s_setprio(0);
    }
    asm volatile("s_waitcnt lgkmcnt(0)" ::: "memory");  // done reading lA[p], lB
    asm volatile("s_barrier" ::: "memory");
    if (t < NT - 1) {
      STAGE_B(t + 1);                                   // overwrite lB
      asm volatile("s_waitcnt vmcnt(0)" ::: "memory");  // B(t+1) + A(t+1) landed
      asm volatile("s_barrier" ::: "memory");
    }
  }
  // K-loop done; all waves past final barrier -> lA reusable as scratch.
  float* scr = (float*)&lA[0][0];        // [128][4] wave partials
  float* scl = scr + 128 * 4;            // [128] final scales

  // per-lane channel constants for its 8 cols (col = wc*128 + ni*16 + lr)
  float g8[8], c8[8], s8[8];
#pragma unroll
  for (int ni = 0; ni < 8; ++ni) {
    int col = wc * 128 + ni * 16 + lr;
    g8[ni] = wg[col]; c8[ni] = chv[col]; s8[ni] = shv[col];
  }

  int rbase_loc = wr * 64 + ((lane >> 4) << 2);        // + mi*16 (+j)
  int rbase_glb = bm * BM + rbase_loc;

#pragma unroll
  for (int mi = 0; mi < 4; ++mi) {
    float4 r1v = *(const float4*)(R1 + rbase_glb + mi * 16);
    float4 r2v = *(const float4*)(R2 + rbase_glb + mi * 16);
    float r1a[4] = {r1v.x, r1v.y, r1v.z, r1v.w};
    float r2a[4] = {r2v.x, r2v.y, r2v.z, r2v.w};
    float ssq[4] = {0.f, 0.f, 0.f, 0.f};
#pragma unroll
    for (int ni = 0; ni < 8; ++ni) {
#pragma unroll
      for (int j = 0; j < 4; ++j) {
        float z = r1a[j] * acc[mi][ni][j] * c8[ni] - r2a[j] * s8[ni];
        float w = z + sqrtf(fmaf(z, z, 1.f));
        float l = fast_log2(w);
        float E = fast_exp2((2.f * g8[ni]) * l);
        float y = 0.5f * (E - fast_rcp(E));
        acc[mi][ni][j] = y;
        ssq[j] += y * y;
      }
    }
#pragma unroll
    for (int j = 0; j < 4; ++j) {
#pragma unroll
      for (int d = 1; d < 16; d <<= 1) ssq[j] += __shfl_xor(ssq[j], d);
    }
    if (lr == 0) {
#pragma unroll
      for (int j = 0; j < 4; ++j)
        scr[(rbase_loc + mi * 16 + j) * 4 + wc] = ssq[j];
    }
  }
  __syncthreads();
  if (tid < 128) {
    float ss = scr[tid * 4] + scr[tid * 4 + 1] + scr[tid * 4 + 2] + scr[tid * 4 + 3];
    float denom = 1.f + sqrtf(1.f + ss);
    float idn = 1.f / denom;
    float nrm = fmaxf(sqrtf(ss) * idn, 1e-15f);
    float maxn = 1.0f - 4e-3f;
    float scale = (nrm > maxn) ? (maxn / nrm) : 1.f;
    scl[tid] = scale * idn;
  }
  __syncthreads();

#pragma unroll
  for (int mi = 0; mi < 4; ++mi) {
    float sc[4];
#pragma unroll
    for (int j = 0; j < 4; ++j) sc[j] = scl[rbase_loc + mi * 16 + j];
#pragma unroll
    for (int ni = 0; ni < 8; ++ni) {
      int col = wc * 128 + ni * 16 + lr;
#pragma unroll
      for (int j = 0; j < 4; ++j)
        out[(size_t)(rbase_glb + mi * 16 + j) * COUT + col] = acc[mi][ni][j] * sc[j];
    }
  }
}

extern "C" void kernel_launch(void* const* d_in, const int* in_sizes, int n_in,
                              void* d_out, int out_size, void* d_ws, size_t ws_size,
                              hipStream_t stream) {
  const float* x    = (const float*)d_in[0];
  const float* wg   = (const float*)d_in[1];
  const float* wv   = (const float*)d_in[2];
  const float* bias = (const float*)d_in[3];
  float* out = (float*)d_out;

  char* ws = (char*)d_ws;
  u16*   U    = (u16*)(ws);                    // 2050*16*512 bf16 = 33,587,200 B
  float* NSQ  = (float*)(ws + 33587200);       // 32800 f32      =    131,200 B
  u16*   WT   = (u16*)(ws + 33718400);         // 512*1536 bf16  =  1,572,864 B
  float* INVN = (float*)(ws + 35291264);       // 512 f32
  float* CH   = (float*)(ws + 35293312);       // 512 f32
  float* SH   = (float*)(ws + 35295360);       // 512 f32
  float* PART = (float*)(ws + 35297408);       // 24*512 f32 = 49,152 B
  float* R1   = (float*)(ws + 35346560);       // 32768 f32 = 131,072 B
  float* R2   = (float*)(ws + 35477632);       // 32768 f32

  double lb = (lgamma(768.0) + lgamma(0.5) - lgamma(768.5))
            - (lgamma(256.0) + lgamma(0.5) - lgamma(256.5));
  float beta_ratio = (float)exp(lb);           // beta(768,.5)/beta(256,.5)

  k_colnorm<<<dim3(COUT / 256, KIN / 64), 256, 0, stream>>>(wv, PART);
  k_fin<<<COUT / 256, 256, 0, stream>>>(PART, INVN);
  k_chsh<<<COUT / 128, 128, 0, stream>>>(bias, CH, SH);
  k_wt<<<dim3(KIN / 64, COUT / 64), 256, 0, stream>>>(wv, INVN, WT);
  k_logmap<<<UROWS, 64, 0, stream>>>(x, U, NSQ, beta_ratio);
  k_rows<<<NROWS / 256, 256, 0, stream>>>(NSQ, R1, R2);
  k_gemm<<<NROWS / BM, 512, 0, stream>>>(U, WT, R1, R2, wg, CH, SH, out);
}